// Round 12
// baseline (151.940 us; speedup 1.0000x reference)
//
#include <hip/hip_runtime.h>
#include <hip/hip_bf16.h>
#include <stdint.h>

#define BTOT 4096
#define RR   64
#define DIMD 128
#define WROW 40   /* wave-buffer row stride in shorts (80 B): bank-friendly */

typedef short s16x8 __attribute__((ext_vector_type(8)));
typedef float f32x4 __attribute__((ext_vector_type(4)));

__device__ __forceinline__ unsigned short f2bf(float x) {
  __hip_bfloat16 h = __float2bfloat16(x);
  return __builtin_bit_cast(unsigned short, h);
}
__device__ __forceinline__ float bf2f(unsigned short u) {
  unsigned int v = ((unsigned int)u) << 16;
  return __builtin_bit_cast(float, v);
}

// ---------------------------------------------------------------------------
// Pre-kernel: qproj[b,k] = sum_d query_r[b,d]*W1[k,128+d] + b1[k]  (fp32),
// offset_emb passthrough, and blocks 0/1 emit XOR-swizzled bf16 copies of
// W1a / W2 into ws.  Swizzle: element (k,d) at k*128 + (d ^ ((k&7)<<3)).
// ---------------------------------------------------------------------------
__global__ __launch_bounds__(256) void prep_kernel(
    const float* __restrict__ W1, const float* __restrict__ b1,
    const float* __restrict__ query_r, const float* __restrict__ W2,
    const float* __restrict__ offset_emb,
    float* __restrict__ qproj, unsigned short* __restrict__ w1a_swz,
    unsigned short* __restrict__ w2_swz, float* __restrict__ out)
{
  __shared__ float w1b[128 * 132];   // +4 pad
  __shared__ float qrs[256];
  const int tid = threadIdx.x;

  { // offset_emb passthrough (1 float4 per thread; 512 blocks cover 4096x128)
    const size_t ob = (size_t)blockIdx.x * 8 * DIMD + (size_t)tid * 4;
    *reinterpret_cast<float4*>(out + (size_t)BTOT * DIMD + ob) =
        *reinterpret_cast<const float4*>(offset_emb + ob);
  }
  { // stage W1b fp32 into padded LDS
    const int k = tid >> 1, d0 = (tid & 1) * 64;
    const float* src = W1 + k * 256 + 128 + d0;
    float* dst = &w1b[k * 132 + d0];
    #pragma unroll
    for (int i = 0; i < 64; i += 4)
      *reinterpret_cast<float4*>(dst + i) = *reinterpret_cast<const float4*>(src + i);
  }
  if (blockIdx.x < 2) { // swizzled bf16 weights
    const float* Wsrc = (blockIdx.x == 0) ? W1 : W2;
    unsigned short* dstw = (blockIdx.x == 0) ? w1a_swz : w2_swz;
    const int stride = (blockIdx.x == 0) ? 256 : 128;
    for (int i = tid; i < 128 * 128; i += 256) {
      const int k = i >> 7, d = i & 127;
      dstw[k * 128 + (d ^ ((k & 7) << 3))] = f2bf(Wsrc[k * stride + d]);
    }
  }
  __syncthreads();

  const int b0 = blockIdx.x * 8;
  const int k = tid & 127, bh = tid >> 7;
  for (int p = 0; p < 4; ++p) {
    const int b = b0 + p * 2;
    qrs[tid] = query_r[(size_t)(b + bh) * DIMD + k];
    __syncthreads();
    float acc = b1[k];
    const float* qq = &qrs[bh * 128];
    const float* wr = &w1b[k * 132];
    #pragma unroll
    for (int d = 0; d < 128; d += 4) {
      float4 wv = *reinterpret_cast<const float4*>(wr + d);
      float4 qv = *reinterpret_cast<const float4*>(qq + d);
      acc = fmaf(wv.x, qv.x, acc); acc = fmaf(wv.y, qv.y, acc);
      acc = fmaf(wv.z, qv.z, acc); acc = fmaf(wv.w, qv.w, acc);
    }
    qproj[(size_t)(b + bh) * DIMD + k] = acc;
    __syncthreads();
  }
}

// ---------------------------------------------------------------------------
// Main kernel: 256 blocks x 512 threads (8 waves); each wave owns TWO b's
// processed as independent interleaved chains (dual per-wave pipeline:
// chain B's global loads are in flight under chain A's MFMA/LDS phases and
// vice versa -> ~2x outstanding bytes at the hardware-pinned 8 waves/CU).
// Body per chain = R8's proven quarter structure (32-wide contraction
// quarters through a 1.25 KB wave-chain buffer; weights in LDS; bias packed
// to regs; the access pattern that measures ~200 MB FETCH). ALL asm fences
// removed (R11 proved DS in-order + compiler lgkmcnt waits are sufficient;
// fences were serializing every phase at full memory latency).
// Grid 256 = exactly 1 block/CU (no second sequential block round).
// LDS = 64 KB weights + 8 waves x 2 chains x 1.25 KB = 84 KB.
// Bare __launch_bounds__(512): the only codegen family that never spilled;
// dual-chain transients ~200-230 VGPR fit the 256 cap at 2 waves/SIMD.
// ---------------------------------------------------------------------------
__global__ __launch_bounds__(512) void main_kernel(
    const float* __restrict__ query_emb,
    const float* __restrict__ refer_embs, const float* __restrict__ refer_r,
    const float* __restrict__ start_embs, const float* __restrict__ b2,
    const float* __restrict__ qproj, const unsigned short* __restrict__ w1a_swz,
    const unsigned short* __restrict__ w2_swz, float* __restrict__ out)
{
  __shared__ unsigned short lds_w1a[128 * 128];   // 32 KB, swizzled
  __shared__ unsigned short lds_w2[128 * 128];    // 32 KB, swizzled
  __shared__ unsigned short tq[8][2][16 * WROW];  // 1.25 KB per wave-chain

  const int tid  = threadIdx.x;
  const int wave = tid >> 6;
  const int lane = tid & 63;
  const int g    = lane >> 4;   // k-group
  const int c    = lane & 15;   // row/col-in-tile

  { // stage swizzled weights (linear uint4 copy; swizzle pre-applied in ws)
    const uint4* s1 = reinterpret_cast<const uint4*>(w1a_swz);
    const uint4* s2 = reinterpret_cast<const uint4*>(w2_swz);
    uint4* d1 = reinterpret_cast<uint4*>(lds_w1a);
    uint4* d2 = reinterpret_cast<uint4*>(lds_w2);
    #pragma unroll
    for (int i = 0; i < 4; ++i) {
      d1[tid + 512 * i] = s1[tid + 512 * i];
      d2[tid + 512 * i] = s2[tid + 512 * i];
    }
  }
  __syncthreads();   // the ONLY barrier

  const int srl = lane >> 2;           // staging local row 0..15
  const int q   = lane & 3;            // staging quarter-of-row (8 floats)
  const int swc = (c & 7) << 3;        // weight swizzle for row nt*16+c
  const int rl4 = 4 * g;

  const int bA = blockIdx.x * 16 + wave * 2;   // this wave's b pair
  unsigned short* tch[2] = { &tq[wave][0][0], &tq[wave][1][0] };

  float qn[2][8], acc[2][8], b2v[8];
  #pragma unroll
  for (int nt = 0; nt < 8; ++nt) {
    b2v[nt] = b2[nt * 16 + c];
    #pragma unroll
    for (int j = 0; j < 2; ++j) {
      qn[j][nt]  = qproj[(size_t)(bA + j) * DIMD + nt * 16 + c];
      acc[j][nt] = 0.f;
    }
  }

  for (int it = 0; it < 4; ++it) {
    size_t rowbase[2];
    #pragma unroll
    for (int j = 0; j < 2; ++j)
      rowbase[j] = ((size_t)(bA + j) * RR + it * 16 + srl) * DIMD;

    float4 rv[2][2], ev[2][2], sv[2][2];
    #pragma unroll
    for (int j = 0; j < 2; ++j) {   // prologue: quarter 0 loads, both chains
      const size_t gb = rowbase[j] + q * 8;
      rv[j][0] = *reinterpret_cast<const float4*>(refer_r    + gb);
      rv[j][1] = *reinterpret_cast<const float4*>(refer_r    + gb + 4);
      ev[j][0] = *reinterpret_cast<const float4*>(refer_embs + gb);
      ev[j][1] = *reinterpret_cast<const float4*>(refer_embs + gb + 4);
      sv[j][0] = *reinterpret_cast<const float4*>(start_embs + gb);
      sv[j][1] = *reinterpret_cast<const float4*>(start_embs + gb + 4);
    }

    uint4 bp[2][4];
    f32x4 Ch[2][8];
    #pragma unroll
    for (int j = 0; j < 2; ++j)
      #pragma unroll
      for (int nt = 0; nt < 8; ++nt)
        Ch[j][nt] = (f32x4){qn[j][nt], qn[j][nt], qn[j][nt], qn[j][nt]};

    // ================= GEMM1 (four 32-wide d-quarters, dual chain) ========
    #pragma unroll
    for (int Q = 0; Q < 4; ++Q) {
      #pragma unroll
      for (int j = 0; j < 2; ++j) {
        { // stage refer_r quarter (one uint4 per lane)
          union { unsigned short u[8]; uint4 v; } pk;
          pk.u[0] = f2bf(rv[j][0].x); pk.u[1] = f2bf(rv[j][0].y);
          pk.u[2] = f2bf(rv[j][0].z); pk.u[3] = f2bf(rv[j][0].w);
          pk.u[4] = f2bf(rv[j][1].x); pk.u[5] = f2bf(rv[j][1].y);
          pk.u[6] = f2bf(rv[j][1].z); pk.u[7] = f2bf(rv[j][1].w);
          *reinterpret_cast<uint4*>(&tch[j][srl * WROW + q * 8]) = pk.v;
        }
        { // bias quarter = ev - sv - rv, packed bf16 (row layout, in regs)
          union { unsigned short u[8]; uint4 v; } pk;
          pk.u[0] = f2bf(ev[j][0].x - sv[j][0].x - rv[j][0].x);
          pk.u[1] = f2bf(ev[j][0].y - sv[j][0].y - rv[j][0].y);
          pk.u[2] = f2bf(ev[j][0].z - sv[j][0].z - rv[j][0].z);
          pk.u[3] = f2bf(ev[j][0].w - sv[j][0].w - rv[j][0].w);
          pk.u[4] = f2bf(ev[j][1].x - sv[j][1].x - rv[j][1].x);
          pk.u[5] = f2bf(ev[j][1].y - sv[j][1].y - rv[j][1].y);
          pk.u[6] = f2bf(ev[j][1].z - sv[j][1].z - rv[j][1].z);
          pk.u[7] = f2bf(ev[j][1].w - sv[j][1].w - rv[j][1].w);
          bp[j][Q] = pk.v;
        }
      }
      if (Q < 3) {  // refill in-flight loads for next quarter, both chains
        #pragma unroll
        for (int j = 0; j < 2; ++j) {
          const size_t gb = rowbase[j] + (Q + 1) * 32 + q * 8;
          rv[j][0] = *reinterpret_cast<const float4*>(refer_r    + gb);
          rv[j][1] = *reinterpret_cast<const float4*>(refer_r    + gb + 4);
          ev[j][0] = *reinterpret_cast<const float4*>(refer_embs + gb);
          ev[j][1] = *reinterpret_cast<const float4*>(refer_embs + gb + 4);
          sv[j][0] = *reinterpret_cast<const float4*>(start_embs + gb);
          sv[j][1] = *reinterpret_cast<const float4*>(start_embs + gb + 4);
        }
      }
      #pragma unroll
      for (int j = 0; j < 2; ++j) {
        const s16x8 af = *reinterpret_cast<const s16x8*>(&tch[j][c * WROW + g * 8]);
        #pragma unroll
        for (int nt = 0; nt < 8; ++nt) {
          s16x8 wf = *reinterpret_cast<const s16x8*>(
              &lds_w1a[(nt * 16 + c) * DIMD + ((Q * 32 + g * 8) ^ swc)]);
          Ch[j][nt] = __builtin_amdgcn_mfma_f32_16x16x32_bf16(af, wf, Ch[j][nt], 0, 0, 0);
        }
      }
    }

    // ================= GEMM2 (four 32-wide k_hid-quarters, dual) ==========
    f32x4 Ca[2][8];
    #pragma unroll
    for (int j = 0; j < 2; ++j)
      #pragma unroll
      for (int nt = 0; nt < 8; ++nt)
        Ca[j][nt] = (f32x4){b2v[nt], b2v[nt], b2v[nt], b2v[nt]};
    #pragma unroll
    for (int Q = 0; Q < 4; ++Q) {
      #pragma unroll
      for (int j = 0; j < 2; ++j)
        #pragma unroll
        for (int ntl = 0; ntl < 2; ++ntl)
          #pragma unroll
          for (int r = 0; r < 4; ++r)
            tch[j][(rl4 + r) * WROW + ntl * 16 + c] =
                f2bf(fmaxf(Ch[j][2 * Q + ntl][r], 0.f));
      #pragma unroll
      for (int j = 0; j < 2; ++j) {
        const s16x8 hf = *reinterpret_cast<const s16x8*>(&tch[j][c * WROW + g * 8]);
        #pragma unroll
        for (int nt = 0; nt < 8; ++nt) {
          s16x8 wf = *reinterpret_cast<const s16x8*>(
              &lds_w2[(nt * 16 + c) * DIMD + ((Q * 32 + g * 8) ^ swc)]);
          Ca[j][nt] = __builtin_amdgcn_mfma_f32_16x16x32_bf16(hf, wf, Ca[j][nt], 0, 0, 0);
        }
      }
    }

    // ================= bias dot + reduce (four quarters, dual) ============
    #pragma unroll
    for (int Q = 0; Q < 4; ++Q) {
      #pragma unroll
      for (int j = 0; j < 2; ++j)
        *reinterpret_cast<uint4*>(&tch[j][srl * WROW + q * 8]) = bp[j][Q];
      #pragma unroll
      for (int j = 0; j < 2; ++j)
        #pragma unroll
        for (int ntl = 0; ntl < 2; ++ntl) {
          const int nt = 2 * Q + ntl;
          float s = 0.f;
          #pragma unroll
          for (int r = 0; r < 4; ++r) {
            const float bcv = bf2f(tch[j][(rl4 + r) * WROW + ntl * 16 + c]);
            s = fmaf(Ca[j][nt][r], bcv, s);
          }
          s += __shfl_xor(s, 16);
          s += __shfl_xor(s, 32);
          acc[j][nt] += s;
        }
    }
  }

  // ---- epilogue
  if (lane < 16) {
    #pragma unroll
    for (int j = 0; j < 2; ++j)
      #pragma unroll
      for (int nt = 0; nt < 8; ++nt)
        out[(size_t)(bA + j) * DIMD + nt * 16 + c] =
            query_emb[(size_t)(bA + j) * DIMD + nt * 16 + c] + acc[j][nt];
  }
}

extern "C" void kernel_launch(void* const* d_in, const int* in_sizes, int n_in,
                              void* d_out, int out_size, void* d_ws, size_t ws_size,
                              hipStream_t stream) {
  const float* query_emb  = (const float*)d_in[0];
  const float* offset_emb = (const float*)d_in[1];
  const float* refer_embs = (const float*)d_in[2];
  const float* query_r    = (const float*)d_in[3];
  const float* refer_r    = (const float*)d_in[4];
  const float* start_embs = (const float*)d_in[5];
  const float* W1 = (const float*)d_in[6];
  const float* b1 = (const float*)d_in[7];
  const float* W2 = (const float*)d_in[8];
  const float* b2 = (const float*)d_in[9];
  float* out = (float*)d_out;

  float* qproj = (float*)d_ws;                       // 4096*128 f32 = 2 MB
  unsigned short* w1a_swz =
      (unsigned short*)((char*)d_ws + (size_t)BTOT * DIMD * sizeof(float));
  unsigned short* w2_swz = w1a_swz + 128 * 128;      // +32 KB each

  hipLaunchKernelGGL(prep_kernel, dim3(512), dim3(256), 0, stream,
                     W1, b1, query_r, W2, offset_emb, qproj, w1a_swz, w2_swz, out);
  hipLaunchKernelGGL(main_kernel, dim3(256), dim3(512), 0, stream,
                     query_emb, refer_embs, refer_r, start_embs,
                     b2, qproj, w1a_swz, w2_swz, out);
}